// Round 1
// baseline (226.915 us; speedup 1.0000x reference)
//
#include <hip/hip_runtime.h>

// Problem: B=8, S=2048, H=1024, D=64. fp32 in, fp32 out.
// out = softmax_causal(q k^T) / sqrt(H) @ v   (softmax FIRST, then /32)

typedef float     f32x4 __attribute__((ext_vector_type(4)));
typedef _Float16  f16x8 __attribute__((ext_vector_type(8)));

__device__ __forceinline__ float wave_max16(float v) {
  #pragma unroll
  for (int off = 1; off < 16; off <<= 1) v = fmaxf(v, __shfl_xor(v, off, 64));
  return v;
}
__device__ __forceinline__ float wave_sum16(float v) {
  #pragma unroll
  for (int off = 1; off < 16; off <<= 1) v += __shfl_xor(v, off, 64);
  return v;
}

// ---------------------------------------------------------------------------
// Kernel 1: Wt[n][k] = f16( W*[k][n] ), n in [0,192) over {Wq|Wk|Wv}, k in [0,1024)
// Transposed so GEMM B-fragments (8 consecutive k at fixed n) are contiguous 16B.
__global__ __launch_bounds__(256) void wt_prep(const float* __restrict__ Wq,
                                               const float* __restrict__ Wk,
                                               const float* __restrict__ Wv,
                                               _Float16* __restrict__ Wt) {
  int id = blockIdx.x * 256 + threadIdx.x;     // 768 blocks * 256 = 196608 exact
  int n = id >> 10;
  int k = id & 1023;
  const float* src = (n < 64) ? Wq : (n < 128 ? Wk : Wv);
  Wt[id] = (_Float16)src[k * 64 + (n & 63)];
}

// ---------------------------------------------------------------------------
// Kernel 2: QKV projection. grid 256 (M-tile=64 rows), 256 threads (4 waves).
// Each wave: 16 rows x 192 cols via 12 mfma_f32_16x16x32_f16 tiles.
// x fp32 -> f16 converted in registers -> padded LDS. B-frags from global (L1/L2).
__global__ __launch_bounds__(256) void qkv_gemm(const float* __restrict__ x,
                                                const _Float16* __restrict__ Wt,
                                                const float* __restrict__ bq,
                                                const float* __restrict__ bk,
                                                const float* __restrict__ bv,
                                                _Float16* __restrict__ qo,
                                                _Float16* __restrict__ ko,
                                                _Float16* __restrict__ vt) {
  __shared__ _Float16 xs[64][72];              // pad 64->72: dword stride 36 == 4 mod 32
  const int tid  = threadIdx.x;
  const int wave = tid >> 6, lane = tid & 63;
  const int l16  = lane & 15, quad = lane >> 4;
  const int m0   = blockIdx.x * 64;
  const int sr   = tid >> 2;                   // staging row 0..63
  const int sc   = (tid & 3) * 16;             // staging col {0,16,32,48}

  f32x4 acc[12];
  #pragma unroll
  for (int i = 0; i < 12; ++i) acc[i] = (f32x4){0.f, 0.f, 0.f, 0.f};

  const float* xrow = x + (size_t)(m0 + sr) * 1024 + sc;

  for (int kk = 0; kk < 1024; kk += 64) {
    f32x4 f0 = *(const f32x4*)(xrow + kk);
    f32x4 f1 = *(const f32x4*)(xrow + kk + 4);
    f32x4 f2 = *(const f32x4*)(xrow + kk + 8);
    f32x4 f3 = *(const f32x4*)(xrow + kk + 12);
    __syncthreads();                           // previous iter done reading xs
    f16x8 h0, h1;
    #pragma unroll
    for (int j = 0; j < 4; ++j) {
      h0[j] = (_Float16)f0[j]; h0[4 + j] = (_Float16)f1[j];
      h1[j] = (_Float16)f2[j]; h1[4 + j] = (_Float16)f3[j];
    }
    *(f16x8*)&xs[sr][sc]     = h0;
    *(f16x8*)&xs[sr][sc + 8] = h1;
    __syncthreads();
    #pragma unroll
    for (int ks = 0; ks < 64; ks += 32) {
      f16x8 a = *(const f16x8*)&xs[wave * 16 + l16][ks + quad * 8];
      #pragma unroll
      for (int nt = 0; nt < 12; ++nt) {
        f16x8 bfr = *(const f16x8*)&Wt[(size_t)(nt * 16 + l16) * 1024 + kk + ks + quad * 8];
        acc[nt] = __builtin_amdgcn_mfma_f32_16x16x32_f16(a, bfr, acc[nt], 0, 0, 0);
      }
    }
  }

  // Epilogue: C/D layout col=lane&15, row=quad*4+reg. Add bias, write f16.
  #pragma unroll
  for (int nt = 0; nt < 12; ++nt) {
    int col = nt * 16 + l16;
    float bias = (nt < 4) ? bq[col] : (nt < 8) ? bk[col - 64] : bv[col - 128];
    #pragma unroll
    for (int r = 0; r < 4; ++r) {
      int m = m0 + wave * 16 + quad * 4 + r;   // global row = b*2048+s
      _Float16 hv = (_Float16)(acc[nt][r] + bias);
      if (nt < 4)      qo[(size_t)m * 64 + col] = hv;
      else if (nt < 8) ko[(size_t)m * 64 + (col - 64)] = hv;
      else {                                   // v stored transposed: vt[b][d][s]
        int b = m >> 11, s = m & 2047;
        vt[((size_t)b * 64 + (col - 128)) * 2048 + s] = hv;
      }
    }
  }
}

// ---------------------------------------------------------------------------
// Kernel 3: causal attention, flash-style online softmax.
// 1024 blocks x 64 threads: 1 wave owns a 16-row q-tile, iterates KV in 64-chunks.
// Heavy tiles get low blockIdx (dispatch first) to smooth the causal imbalance.
__global__ __launch_bounds__(64) void attn(const _Float16* __restrict__ q,
                                           const _Float16* __restrict__ k,
                                           const _Float16* __restrict__ vt,
                                           float* __restrict__ out) {
  const int blk  = blockIdx.x;
  const int qt   = 127 - (blk >> 3);           // q-tile 0..127 (heavy first)
  const int b    = blk & 7;
  const int lane = threadIdx.x;
  const int l16  = lane & 15, quad = lane >> 4;
  const int q0   = qt * 16;

  __shared__ _Float16 P[16][72];               // C-layout -> A-layout transpose buffer

  const _Float16* qb = q  + (size_t)b * 2048 * 64;
  const _Float16* kb = k  + (size_t)b * 2048 * 64;
  const _Float16* vb = vt + (size_t)b * 64 * 2048;

  // Q A-frags held in registers for the whole KV loop: A[m=l16][kdim=quad*8+j]
  f16x8 qf0 = *(const f16x8*)&qb[(q0 + l16) * 64 + quad * 8];
  f16x8 qf1 = *(const f16x8*)&qb[(q0 + l16) * 64 + 32 + quad * 8];

  f32x4 o[4];
  #pragma unroll
  for (int i = 0; i < 4; ++i) o[i] = (f32x4){0.f, 0.f, 0.f, 0.f};
  float mrow[4] = {-1e30f, -1e30f, -1e30f, -1e30f};
  float lrow[4] = {0.f, 0.f, 0.f, 0.f};
  const float L2E = 1.44269504088896340736f;

  const int kvend = q0 + 16;                   // causal: skv <= sq <= q0+15
  for (int kv0 = 0; kv0 < kvend; kv0 += 64) {
    // --- QK^T: 4 score tiles of 16 kv each (reference applies NO logit scale)
    f32x4 sc[4];
    #pragma unroll
    for (int t = 0; t < 4; ++t) {
      int kvc = kv0 + t * 16;
      f32x4 c = (f32x4){0.f, 0.f, 0.f, 0.f};
      if (kvc < kvend) {                       // skip fully-masked tiles
        f16x8 kf0 = *(const f16x8*)&kb[(kvc + l16) * 64 + quad * 8];
        f16x8 kf1 = *(const f16x8*)&kb[(kvc + l16) * 64 + 32 + quad * 8];
        c = __builtin_amdgcn_mfma_f32_16x16x32_f16(qf0, kf0, c, 0, 0, 0);
        c = __builtin_amdgcn_mfma_f32_16x16x32_f16(qf1, kf1, c, 0, 0, 0);
      }
      sc[t] = c;
    }
    // --- causal mask (only diagonal-crossing iterations need it)
    if (kv0 + 63 > q0) {
      #pragma unroll
      for (int t = 0; t < 4; ++t) {
        int skv = kv0 + t * 16 + l16;          // C/D col = key index
        #pragma unroll
        for (int r = 0; r < 4; ++r) {
          int sq = q0 + quad * 4 + r;          // C/D row = query index
          if (skv > sq) sc[t][r] = -1e30f;
        }
      }
    }
    // --- online softmax (exp2 domain); rows live across the 16 lanes of a quad
    float alpha[4];
    #pragma unroll
    for (int r = 0; r < 4; ++r) {
      float mx = fmaxf(fmaxf(sc[0][r], sc[1][r]), fmaxf(sc[2][r], sc[3][r]));
      mx = wave_max16(mx);
      float mnew = fmaxf(mrow[r], mx);
      alpha[r] = exp2f((mrow[r] - mnew) * L2E);
      mrow[r] = mnew;
    }
    #pragma unroll
    for (int t = 0; t < 4; ++t)
      #pragma unroll
      for (int r = 0; r < 4; ++r)
        sc[t][r] = exp2f((sc[t][r] - mrow[r]) * L2E);   // masked -> exp2(-huge)=0
    #pragma unroll
    for (int r = 0; r < 4; ++r) {
      float s = sc[0][r] + sc[1][r] + sc[2][r] + sc[3][r];
      s = wave_sum16(s);
      lrow[r] = lrow[r] * alpha[r] + s;
      #pragma unroll
      for (int dt = 0; dt < 4; ++dt) o[dt][r] *= alpha[r];
    }
    // --- P: C-layout -> A-layout via LDS (f16)
    #pragma unroll
    for (int t = 0; t < 4; ++t)
      #pragma unroll
      for (int r = 0; r < 4; ++r)
        P[quad * 4 + r][t * 16 + l16] = (_Float16)sc[t][r];
    __syncthreads();                           // single wave: compiles to waitcnt+barrier
    f16x8 p0 = *(const f16x8*)&P[l16][quad * 8];
    f16x8 p1 = *(const f16x8*)&P[l16][32 + quad * 8];
    // --- PV: B-frags contiguous thanks to transposed v (vt[b][d][s])
    #pragma unroll
    for (int dt = 0; dt < 4; ++dt) {
      f16x8 v0 = *(const f16x8*)&vb[(size_t)(dt * 16 + l16) * 2048 + kv0 + quad * 8];
      f16x8 v1 = *(const f16x8*)&vb[(size_t)(dt * 16 + l16) * 2048 + kv0 + 32 + quad * 8];
      o[dt] = __builtin_amdgcn_mfma_f32_16x16x32_f16(p0, v0, o[dt], 0, 0, 0);
      o[dt] = __builtin_amdgcn_mfma_f32_16x16x32_f16(p1, v1, o[dt], 0, 0, 0);
    }
    __syncthreads();                           // P reused next iteration
  }

  // Epilogue: out = o / (l * sqrt(H));  sqrt(1024)=32 applied AFTER softmax (ref quirk)
  #pragma unroll
  for (int r = 0; r < 4; ++r) {
    float inv = 1.0f / (lrow[r] * 32.0f);
    #pragma unroll
    for (int dt = 0; dt < 4; ++dt)
      out[((size_t)b * 2048 + q0 + quad * 4 + r) * 64 + dt * 16 + l16] = o[dt][r] * inv;
  }
}

// ---------------------------------------------------------------------------
extern "C" void kernel_launch(void* const* d_in, const int* in_sizes, int n_in,
                              void* d_out, int out_size, void* d_ws, size_t ws_size,
                              hipStream_t stream) {
  const float* x  = (const float*)d_in[0];
  const float* Wq = (const float*)d_in[1];
  const float* bq = (const float*)d_in[2];
  const float* Wk = (const float*)d_in[3];
  const float* bk = (const float*)d_in[4];
  const float* Wv = (const float*)d_in[5];
  const float* bv = (const float*)d_in[6];
  float* out = (float*)d_out;

  // ws layout (f16): Wt 192*1024 | q 16384*64 | k 16384*64 | vt 8*64*2048  (~6.7 MB)
  _Float16* Wt = (_Float16*)d_ws;
  _Float16* qo = Wt + 192 * 1024;
  _Float16* ko = qo + 16384 * 64;
  _Float16* vt = ko + 16384 * 64;

  hipLaunchKernelGGL(wt_prep,  dim3(768),  dim3(256), 0, stream, Wq, Wk, Wv, Wt);
  hipLaunchKernelGGL(qkv_gemm, dim3(256),  dim3(256), 0, stream, x, Wt, bq, bk, bv, qo, ko, vt);
  hipLaunchKernelGGL(attn,     dim3(1024), dim3(64),  0, stream, qo, ko, vt, out);
}

// Round 2
// 186.121 us; speedup vs baseline: 1.2192x; 1.2192x over previous
//
#include <hip/hip_runtime.h>

// Problem: B=8, S=2048, H=1024, D=64. fp32 in, fp32 out.
// out = softmax_causal(q k^T) / sqrt(H) @ v   (softmax FIRST, then /32)

typedef float     f32x4 __attribute__((ext_vector_type(4)));
typedef _Float16  f16x8 __attribute__((ext_vector_type(8)));

__device__ __forceinline__ float wave_max16(float v) {
  #pragma unroll
  for (int off = 1; off < 16; off <<= 1) v = fmaxf(v, __shfl_xor(v, off, 64));
  return v;
}
__device__ __forceinline__ float wave_sum16(float v) {
  #pragma unroll
  for (int off = 1; off < 16; off <<= 1) v += __shfl_xor(v, off, 64);
  return v;
}

// ---------------------------------------------------------------------------
// Kernel 1: pack W{q,k,v} into MFMA B-fragment order, f16.
// Frag f = (kstep*12 + nt)*64 + lane holds 8 f16:
//   element j = W[n = nt*16 + (lane&15)][k = kstep*32 + (lane>>4)*8 + j]
// so the GEMM's B-frag load is one contiguous, wave-coalesced 1KB read.
__global__ __launch_bounds__(256) void wt_prep(const float* __restrict__ Wq,
                                               const float* __restrict__ Wk,
                                               const float* __restrict__ Wv,
                                               _Float16* __restrict__ WtF) {
  int id = blockIdx.x * 256 + threadIdx.x;     // 96 blocks * 256 = 24576 frags
  int lane  = id & 63;
  int nt    = (id >> 6) % 12;
  int kstep = (id >> 6) / 12;
  int n = nt * 16 + (lane & 15);
  int kbase = kstep * 32 + (lane >> 4) * 8;
  const float* src = (n < 64) ? Wq : (n < 128 ? Wk : Wv);
  int c = n & 63;
  f16x8 h;
  #pragma unroll
  for (int j = 0; j < 8; ++j) h[j] = (_Float16)src[(kbase + j) * 64 + c];
  *(f16x8*)&WtF[(size_t)id * 8] = h;
}

// ---------------------------------------------------------------------------
// Kernel 2: QKV projection. grid 256 (M-tile=64 rows), 256 threads (4 waves).
// Each wave: 16 rows x 192 cols via 12 mfma_f32_16x16x32_f16 tiles.
// x fp32 -> f16 in registers -> padded LDS. B-frags: coalesced WtF loads
// (L1-resident: all 4 waves read identical fragments).
__global__ __launch_bounds__(256) void qkv_gemm(const float* __restrict__ x,
                                                const _Float16* __restrict__ WtF,
                                                const float* __restrict__ bq,
                                                const float* __restrict__ bk,
                                                const float* __restrict__ bv,
                                                _Float16* __restrict__ qo,
                                                _Float16* __restrict__ ko,
                                                _Float16* __restrict__ vt) {
  __shared__ _Float16 xs[64][72];              // pad: dword stride 36 -> 2-way alias only
  const int tid  = threadIdx.x;
  const int wave = tid >> 6, lane = tid & 63;
  const int l16  = lane & 15, quad = lane >> 4;
  const int m0   = blockIdx.x * 64;
  const int sr   = tid >> 2;                   // staging row 0..63
  const int sc   = (tid & 3) * 16;             // staging col {0,16,32,48}

  f32x4 acc[12];
  #pragma unroll
  for (int i = 0; i < 12; ++i) acc[i] = (f32x4){0.f, 0.f, 0.f, 0.f};

  const float* xrow = x + (size_t)(m0 + sr) * 1024 + sc;

  for (int kk = 0; kk < 1024; kk += 64) {
    f32x4 f0 = *(const f32x4*)(xrow + kk);
    f32x4 f1 = *(const f32x4*)(xrow + kk + 4);
    f32x4 f2 = *(const f32x4*)(xrow + kk + 8);
    f32x4 f3 = *(const f32x4*)(xrow + kk + 12);
    __syncthreads();                           // previous iter done reading xs
    f16x8 h0, h1;
    #pragma unroll
    for (int j = 0; j < 4; ++j) {
      h0[j] = (_Float16)f0[j]; h0[4 + j] = (_Float16)f1[j];
      h1[j] = (_Float16)f2[j]; h1[4 + j] = (_Float16)f3[j];
    }
    *(f16x8*)&xs[sr][sc]     = h0;
    *(f16x8*)&xs[sr][sc + 8] = h1;
    __syncthreads();
    #pragma unroll
    for (int ks = 0; ks < 64; ks += 32) {
      f16x8 a = *(const f16x8*)&xs[wave * 16 + l16][ks + quad * 8];
      const _Float16* bbase = WtF + ((size_t)(((kk + ks) >> 5) * 12) * 64 + lane) * 8;
      #pragma unroll
      for (int nt = 0; nt < 12; ++nt) {
        f16x8 bfr = *(const f16x8*)(bbase + (size_t)nt * 64 * 8);
        acc[nt] = __builtin_amdgcn_mfma_f32_16x16x32_f16(a, bfr, acc[nt], 0, 0, 0);
      }
    }
  }

  // Epilogue: C/D layout col=lane&15, row=quad*4+reg. Add bias, write f16.
  #pragma unroll
  for (int nt = 0; nt < 12; ++nt) {
    int col = nt * 16 + l16;
    float bias = (nt < 4) ? bq[col] : (nt < 8) ? bk[col - 64] : bv[col - 128];
    #pragma unroll
    for (int r = 0; r < 4; ++r) {
      int m = m0 + wave * 16 + quad * 4 + r;   // global row = b*2048+s
      _Float16 hv = (_Float16)(acc[nt][r] + bias);
      if (nt < 4)      qo[(size_t)m * 64 + col] = hv;
      else if (nt < 8) ko[(size_t)m * 64 + (col - 64)] = hv;
      else {                                   // v stored transposed: vt[b][d][s]
        int b = m >> 11, s = m & 2047;
        vt[((size_t)b * 64 + (col - 128)) * 2048 + s] = hv;
      }
    }
  }
}

// ---------------------------------------------------------------------------
// Kernel 3: causal attention, flash-style online softmax, in-block split-KV.
// 1024 blocks x 256 threads (4 waves). All 4 waves share one 16-row q-tile;
// wave w handles KV chunks w*64, w*64+256, ... with private (m,l,o) state,
// merged once through LDS at the end. 16 waves/CU vs round-1's 4.
__global__ __launch_bounds__(256) void attn(const _Float16* __restrict__ q,
                                            const _Float16* __restrict__ k,
                                            const _Float16* __restrict__ vt,
                                            float* __restrict__ out) {
  const int blk  = blockIdx.x;
  const int qt   = 127 - (blk >> 3);           // q-tile 0..127 (heavy first)
  const int b    = blk & 7;
  const int tid  = threadIdx.x;
  const int wave = tid >> 6, lane = tid & 63;
  const int l16  = lane & 15, quad = lane >> 4;
  const int q0   = qt * 16;

  __shared__ _Float16 P[4][16][72];            // per-wave C->A transpose buffer
  __shared__ float    ob[4][16][66];           // per-wave partial O
  __shared__ float    mlb[4][2][16];           // per-wave (m, l) per row

  const _Float16* qb = q  + (size_t)b * 2048 * 64;
  const _Float16* kb = k  + (size_t)b * 2048 * 64;
  const _Float16* vb = vt + (size_t)b * 64 * 2048;

  // Q A-frags held in registers for the whole KV loop: A[m=l16][kdim=quad*8+j]
  f16x8 qf0 = *(const f16x8*)&qb[(q0 + l16) * 64 + quad * 8];
  f16x8 qf1 = *(const f16x8*)&qb[(q0 + l16) * 64 + 32 + quad * 8];

  f32x4 o[4];
  #pragma unroll
  for (int i = 0; i < 4; ++i) o[i] = (f32x4){0.f, 0.f, 0.f, 0.f};
  float mrow[4] = {-1e30f, -1e30f, -1e30f, -1e30f};
  float lrow[4] = {0.f, 0.f, 0.f, 0.f};
  const float L2E = 1.44269504088896340736f;

  const int kvend = q0 + 16;                   // causal: skv <= sq <= q0+15
  for (int kv0 = wave * 64; kv0 < kvend; kv0 += 256) {
    // --- QK^T: 4 score tiles of 16 kv each (reference applies NO logit scale)
    f32x4 sc[4];
    #pragma unroll
    for (int t = 0; t < 4; ++t) {
      int kvc = kv0 + t * 16;
      f32x4 c = (f32x4){0.f, 0.f, 0.f, 0.f};
      if (kvc < kvend) {                       // skip fully-masked tiles
        f16x8 kf0 = *(const f16x8*)&kb[(kvc + l16) * 64 + quad * 8];
        f16x8 kf1 = *(const f16x8*)&kb[(kvc + l16) * 64 + 32 + quad * 8];
        c = __builtin_amdgcn_mfma_f32_16x16x32_f16(qf0, kf0, c, 0, 0, 0);
        c = __builtin_amdgcn_mfma_f32_16x16x32_f16(qf1, kf1, c, 0, 0, 0);
      }
      sc[t] = c;
    }
    // --- causal mask (only the diagonal-crossing chunk needs it)
    if (kv0 + 63 > q0) {
      #pragma unroll
      for (int t = 0; t < 4; ++t) {
        int skv = kv0 + t * 16 + l16;          // C/D col = key index
        #pragma unroll
        for (int r = 0; r < 4; ++r) {
          int sq = q0 + quad * 4 + r;          // C/D row = query index
          if (skv > sq) sc[t][r] = -1e30f;
        }
      }
    }
    // --- online softmax (exp2 domain); rows live across the 16 lanes of a quad
    float alpha[4];
    #pragma unroll
    for (int r = 0; r < 4; ++r) {
      float mx = fmaxf(fmaxf(sc[0][r], sc[1][r]), fmaxf(sc[2][r], sc[3][r]));
      mx = wave_max16(mx);
      float mnew = fmaxf(mrow[r], mx);
      alpha[r] = exp2f((mrow[r] - mnew) * L2E);
      mrow[r] = mnew;
    }
    #pragma unroll
    for (int t = 0; t < 4; ++t)
      #pragma unroll
      for (int r = 0; r < 4; ++r)
        sc[t][r] = exp2f((sc[t][r] - mrow[r]) * L2E);   // masked -> 0
    #pragma unroll
    for (int r = 0; r < 4; ++r) {
      float s = sc[0][r] + sc[1][r] + sc[2][r] + sc[3][r];
      s = wave_sum16(s);
      lrow[r] = lrow[r] * alpha[r] + s;
      #pragma unroll
      for (int dt = 0; dt < 4; ++dt) o[dt][r] *= alpha[r];
    }
    // --- P: C-layout -> A-layout via this wave's private LDS tile.
    // Per-wave DS ops are in-order; compiler barrier + lgkmcnt drain suffices
    // (no __syncthreads: loop trip count differs per wave).
    #pragma unroll
    for (int t = 0; t < 4; ++t)
      #pragma unroll
      for (int r = 0; r < 4; ++r)
        P[wave][quad * 4 + r][t * 16 + l16] = (_Float16)sc[t][r];
    asm volatile("s_waitcnt lgkmcnt(0)" ::: "memory");
    f16x8 p0 = *(const f16x8*)&P[wave][l16][quad * 8];
    f16x8 p1 = *(const f16x8*)&P[wave][l16][32 + quad * 8];
    // --- PV: B-frags contiguous thanks to transposed v (vt[b][d][s])
    #pragma unroll
    for (int dt = 0; dt < 4; ++dt) {
      f16x8 v0 = *(const f16x8*)&vb[(size_t)(dt * 16 + l16) * 2048 + kv0 + quad * 8];
      f16x8 v1 = *(const f16x8*)&vb[(size_t)(dt * 16 + l16) * 2048 + kv0 + 32 + quad * 8];
      o[dt] = __builtin_amdgcn_mfma_f32_16x16x32_f16(p0, v0, o[dt], 0, 0, 0);
      o[dt] = __builtin_amdgcn_mfma_f32_16x16x32_f16(p1, v1, o[dt], 0, 0, 0);
    }
  }

  // --- publish per-wave partials (waves with zero chunks publish m=-1e30, l=0)
  #pragma unroll
  for (int dt = 0; dt < 4; ++dt)
    #pragma unroll
    for (int r = 0; r < 4; ++r)
      ob[wave][quad * 4 + r][dt * 16 + l16] = o[dt][r];
  if (l16 == 0) {
    #pragma unroll
    for (int r = 0; r < 4; ++r) {
      mlb[wave][0][quad * 4 + r] = mrow[r];
      mlb[wave][1][quad * 4 + r] = lrow[r];
    }
  }
  __syncthreads();

  // --- merge 4 splits; thread t -> row t>>4, cols (t&15)*4 .. +3
  {
    int row = tid >> 4;
    int c0  = (tid & 15) * 4;
    float m0 = mlb[0][0][row], m1 = mlb[1][0][row];
    float m2 = mlb[2][0][row], m3 = mlb[3][0][row];
    float M  = fmaxf(fmaxf(m0, m1), fmaxf(m2, m3));
    float w0 = exp2f((m0 - M) * L2E), w1 = exp2f((m1 - M) * L2E);
    float w2 = exp2f((m2 - M) * L2E), w3 = exp2f((m3 - M) * L2E);
    float L  = w0 * mlb[0][1][row] + w1 * mlb[1][1][row]
             + w2 * mlb[2][1][row] + w3 * mlb[3][1][row];
    float inv = 1.0f / (L * 32.0f);            // sqrt(H)=32 applied AFTER softmax
    f32x4 res;
    #pragma unroll
    for (int j = 0; j < 4; ++j)
      res[j] = (w0 * ob[0][row][c0 + j] + w1 * ob[1][row][c0 + j]
              + w2 * ob[2][row][c0 + j] + w3 * ob[3][row][c0 + j]) * inv;
    *(f32x4*)&out[((size_t)b * 2048 + q0 + row) * 64 + c0] = res;
  }
}

// ---------------------------------------------------------------------------
extern "C" void kernel_launch(void* const* d_in, const int* in_sizes, int n_in,
                              void* d_out, int out_size, void* d_ws, size_t ws_size,
                              hipStream_t stream) {
  const float* x  = (const float*)d_in[0];
  const float* Wq = (const float*)d_in[1];
  const float* bq = (const float*)d_in[2];
  const float* Wk = (const float*)d_in[3];
  const float* bk = (const float*)d_in[4];
  const float* Wv = (const float*)d_in[5];
  const float* bv = (const float*)d_in[6];
  float* out = (float*)d_out;

  // ws layout (f16): WtF 192*1024 | q 16384*64 | k 16384*64 | vt 8*64*2048 (~6.7MB)
  _Float16* WtF = (_Float16*)d_ws;
  _Float16* qo  = WtF + 192 * 1024;
  _Float16* ko  = qo + 16384 * 64;
  _Float16* vt  = ko + 16384 * 64;

  hipLaunchKernelGGL(wt_prep,  dim3(96),   dim3(256), 0, stream, Wq, Wk, Wv, WtF);
  hipLaunchKernelGGL(qkv_gemm, dim3(256),  dim3(256), 0, stream, x, WtF, bq, bk, bv, qo, ko, vt);
  hipLaunchKernelGGL(attn,     dim3(1024), dim3(256), 0, stream, qo, ko, vt, out);
}

// Round 3
// 156.166 us; speedup vs baseline: 1.4530x; 1.1918x over previous
//
#include <hip/hip_runtime.h>

// Problem: B=8, S=2048, H=1024, D=64. fp32 in, fp32 out.
// out = softmax_causal(q k^T) / sqrt(H) @ v   (softmax FIRST, then /32)

typedef float     f32x4 __attribute__((ext_vector_type(4)));
typedef _Float16  f16x8 __attribute__((ext_vector_type(8)));
typedef _Float16  f16x4 __attribute__((ext_vector_type(4)));

__device__ __forceinline__ float wave_max16(float v) {
  #pragma unroll
  for (int off = 1; off < 16; off <<= 1) v = fmaxf(v, __shfl_xor(v, off, 64));
  return v;
}
__device__ __forceinline__ float wave_sum16(float v) {
  #pragma unroll
  for (int off = 1; off < 16; off <<= 1) v += __shfl_xor(v, off, 64);
  return v;
}

// ---------------------------------------------------------------------------
// Kernel 1: pack W{q,k,v} into MFMA B-fragment order (f16) via LDS transpose.
// Frag f = (kstep*12 + nt)*64 + lane holds 8 f16:
//   element j = W[n = nt*16 + (lane&15)][k = kstep*32 + (lane>>4)*8 + j]
// Grid 48 = 3 W x 16 k-tiles of 64. Coalesced f32x4 reads; frag-ordered writes.
__global__ __launch_bounds__(256) void wt_prep(const float* __restrict__ Wq,
                                               const float* __restrict__ Wk,
                                               const float* __restrict__ Wv,
                                               _Float16* __restrict__ WtF) {
  const int w  = blockIdx.x >> 4;              // which W
  const int kt = blockIdx.x & 15;              // k-tile of 64
  const float* src = (w == 0) ? Wq : (w == 1 ? Wk : Wv);
  __shared__ _Float16 ls[64][72];              // [local k][n], padded
  const int t = threadIdx.x;
  {
    int rr = t >> 4;                           // 0..15
    int c4 = (t & 15) * 4;
    #pragma unroll
    for (int ri = 0; ri < 4; ++ri) {
      int k = rr + ri * 16;                    // local k 0..63
      f32x4 f = *(const f32x4*)&src[(size_t)(kt * 64 + k) * 64 + c4];
      #pragma unroll
      for (int j = 0; j < 4; ++j) ls[k][c4 + j] = (_Float16)f[j];
    }
  }
  __syncthreads();
  const int lane = t & 63, l16 = lane & 15, quad = lane >> 4;
  #pragma unroll
  for (int h = 0; h < 2; ++h) {
    int fid     = h * 4 + (t >> 6);            // 0..7
    int kstep_l = fid >> 2;                    // 0..1
    int ntl     = fid & 3;                     // 0..3
    int nt      = w * 4 + ntl;
    int kstep   = kt * 2 + kstep_l;
    f16x8 o;
    #pragma unroll
    for (int j = 0; j < 8; ++j) o[j] = ls[kstep_l * 32 + quad * 8 + j][ntl * 16 + l16];
    *(f16x8*)&WtF[((size_t)(kstep * 12 + nt) * 64 + lane) * 8] = o;
  }
}

// ---------------------------------------------------------------------------
// Kernel 2: QKV projection. Grid 512 (M-tile=32), 512 threads (8 waves),
// 2 blocks/CU -> 16 waves/CU. Whole 32x1024 x-tile staged ONCE into a 64KB
// XOR-swizzled LDS buffer (granule=8 f16; phys_g = g ^ (row&7) -> conflict-free
// staging writes AND A-frag ds_read_b128). Single barrier; then each wave
// independently streams 96 coalesced B-frag loads + 96 MFMAs.
// Wave split: mhalf = wave>>2 (16 rows), ngrp = wave&3 (3 n-tiles).
__global__ __launch_bounds__(512, 4) void qkv_gemm(const float* __restrict__ x,
                                                   const _Float16* __restrict__ WtF,
                                                   const float* __restrict__ bq,
                                                   const float* __restrict__ bk,
                                                   const float* __restrict__ bv,
                                                   _Float16* __restrict__ qo,
                                                   _Float16* __restrict__ ko,
                                                   _Float16* __restrict__ vt) {
  __shared__ _Float16 xs[32 * 1024];           // exactly 64 KB
  const int tid  = threadIdx.x;
  const int wave = tid >> 6, lane = tid & 63;
  const int l16  = lane & 15, quad = lane >> 4;
  const int mhalf = wave >> 2;                 // 0..1
  const int ngrp  = wave & 3;                  // 0..3
  const int m0    = blockIdx.x * 32;

  // --- stage x tile (fp32 -> f16), coalesced: 16-lane groups read 256B runs
  {
    int row   = tid >> 4;                      // 0..31
    int cbase = (tid & 15) * 4;
    const float* xrow = x + (size_t)(m0 + row) * 1024;
    int key = row & 7;
    #pragma unroll
    for (int j = 0; j < 16; ++j) {
      int col = cbase + j * 64;
      f32x4 f = *(const f32x4*)&xrow[col];
      f16x4 hh;
      #pragma unroll
      for (int e = 0; e < 4; ++e) hh[e] = (_Float16)f[e];
      int g   = col >> 3;                      // granule index 0..127
      int sub = col & 7;                       // 0 or 4
      *(f16x4*)&xs[(size_t)row * 1024 + (size_t)((g ^ key) << 3) + sub] = hh;
    }
  }
  __syncthreads();

  f32x4 acc0 = (f32x4){0.f,0.f,0.f,0.f};
  f32x4 acc1 = (f32x4){0.f,0.f,0.f,0.f};
  f32x4 acc2 = (f32x4){0.f,0.f,0.f,0.f};

  const int arow = mhalf * 16 + l16;
  const _Float16* abase = xs + (size_t)arow * 1024;
  const int akey = arow & 7;
  const _Float16* wbase = WtF + ((size_t)(ngrp * 3) * 64 + lane) * 8;

  #pragma unroll 4
  for (int kstep = 0; kstep < 32; ++kstep) {
    f16x8 a = *(const f16x8*)(abase + (((kstep * 4 + quad) ^ akey) << 3));
    const _Float16* wk = wbase + (size_t)kstep * (12 * 64 * 8);
    f16x8 b0 = *(const f16x8*)(wk);
    f16x8 b1 = *(const f16x8*)(wk + 512);
    f16x8 b2 = *(const f16x8*)(wk + 1024);
    acc0 = __builtin_amdgcn_mfma_f32_16x16x32_f16(a, b0, acc0, 0, 0, 0);
    acc1 = __builtin_amdgcn_mfma_f32_16x16x32_f16(a, b1, acc1, 0, 0, 0);
    acc2 = __builtin_amdgcn_mfma_f32_16x16x32_f16(a, b2, acc2, 0, 0, 0);
  }

  // --- epilogue: C/D col=lane&15, row=quad*4+r. Bias add, f16 write.
  f32x4 accs[3] = {acc0, acc1, acc2};
  #pragma unroll
  for (int i = 0; i < 3; ++i) {
    int nt  = ngrp * 3 + i;
    int col = nt * 16 + l16;
    float bias = (nt < 4) ? bq[col] : (nt < 8) ? bk[col - 64] : bv[col - 128];
    #pragma unroll
    for (int r = 0; r < 4; ++r) {
      int m = m0 + mhalf * 16 + quad * 4 + r;  // global row = b*2048+s
      _Float16 hv = (_Float16)(accs[i][r] + bias);
      if (nt < 4)      qo[(size_t)m * 64 + col] = hv;
      else if (nt < 8) ko[(size_t)m * 64 + (col - 64)] = hv;
      else {                                   // v stored transposed: vt[b][d][s]
        int b = m >> 11, s = m & 2047;
        vt[((size_t)b * 64 + (col - 128)) * 2048 + s] = hv;
      }
    }
  }
}

// ---------------------------------------------------------------------------
// Kernel 3: causal attention, flash-style online softmax, in-block split-KV.
// 1024 blocks x 256 threads (4 waves), per-wave private (m,l,o), LDS merge.
__global__ __launch_bounds__(256) void attn(const _Float16* __restrict__ q,
                                            const _Float16* __restrict__ k,
                                            const _Float16* __restrict__ vt,
                                            float* __restrict__ out) {
  const int blk  = blockIdx.x;
  const int qt   = 127 - (blk >> 3);           // q-tile 0..127 (heavy first)
  const int b    = blk & 7;
  const int tid  = threadIdx.x;
  const int wave = tid >> 6, lane = tid & 63;
  const int l16  = lane & 15, quad = lane >> 4;
  const int q0   = qt * 16;

  __shared__ _Float16 P[4][16][72];            // per-wave C->A transpose buffer
  __shared__ float    ob[4][16][66];           // per-wave partial O
  __shared__ float    mlb[4][2][16];           // per-wave (m, l) per row

  const _Float16* qb = q  + (size_t)b * 2048 * 64;
  const _Float16* kb = k  + (size_t)b * 2048 * 64;
  const _Float16* vb = vt + (size_t)b * 64 * 2048;

  f16x8 qf0 = *(const f16x8*)&qb[(q0 + l16) * 64 + quad * 8];
  f16x8 qf1 = *(const f16x8*)&qb[(q0 + l16) * 64 + 32 + quad * 8];

  f32x4 o[4];
  #pragma unroll
  for (int i = 0; i < 4; ++i) o[i] = (f32x4){0.f, 0.f, 0.f, 0.f};
  float mrow[4] = {-1e30f, -1e30f, -1e30f, -1e30f};
  float lrow[4] = {0.f, 0.f, 0.f, 0.f};
  const float L2E = 1.44269504088896340736f;

  const int kvend = q0 + 16;                   // causal: skv <= sq <= q0+15
  for (int kv0 = wave * 64; kv0 < kvend; kv0 += 256) {
    f32x4 sc[4];
    #pragma unroll
    for (int t = 0; t < 4; ++t) {
      int kvc = kv0 + t * 16;
      f32x4 c = (f32x4){0.f, 0.f, 0.f, 0.f};
      if (kvc < kvend) {                       // skip fully-masked tiles
        f16x8 kf0 = *(const f16x8*)&kb[(kvc + l16) * 64 + quad * 8];
        f16x8 kf1 = *(const f16x8*)&kb[(kvc + l16) * 64 + 32 + quad * 8];
        c = __builtin_amdgcn_mfma_f32_16x16x32_f16(qf0, kf0, c, 0, 0, 0);
        c = __builtin_amdgcn_mfma_f32_16x16x32_f16(qf1, kf1, c, 0, 0, 0);
      }
      sc[t] = c;
    }
    if (kv0 + 63 > q0) {                       // causal mask on diagonal chunk
      #pragma unroll
      for (int t = 0; t < 4; ++t) {
        int skv = kv0 + t * 16 + l16;
        #pragma unroll
        for (int r = 0; r < 4; ++r) {
          int sq = q0 + quad * 4 + r;
          if (skv > sq) sc[t][r] = -1e30f;
        }
      }
    }
    float alpha[4];
    #pragma unroll
    for (int r = 0; r < 4; ++r) {
      float mx = fmaxf(fmaxf(sc[0][r], sc[1][r]), fmaxf(sc[2][r], sc[3][r]));
      mx = wave_max16(mx);
      float mnew = fmaxf(mrow[r], mx);
      alpha[r] = exp2f((mrow[r] - mnew) * L2E);
      mrow[r] = mnew;
    }
    #pragma unroll
    for (int t = 0; t < 4; ++t)
      #pragma unroll
      for (int r = 0; r < 4; ++r)
        sc[t][r] = exp2f((sc[t][r] - mrow[r]) * L2E);
    #pragma unroll
    for (int r = 0; r < 4; ++r) {
      float s = sc[0][r] + sc[1][r] + sc[2][r] + sc[3][r];
      s = wave_sum16(s);
      lrow[r] = lrow[r] * alpha[r] + s;
      #pragma unroll
      for (int dt = 0; dt < 4; ++dt) o[dt][r] *= alpha[r];
    }
    // P: C-layout -> A-layout via this wave's private LDS tile (per-wave DS
    // ordering; explicit lgkmcnt drain instead of block barrier).
    #pragma unroll
    for (int t = 0; t < 4; ++t)
      #pragma unroll
      for (int r = 0; r < 4; ++r)
        P[wave][quad * 4 + r][t * 16 + l16] = (_Float16)sc[t][r];
    asm volatile("s_waitcnt lgkmcnt(0)" ::: "memory");
    f16x8 p0 = *(const f16x8*)&P[wave][l16][quad * 8];
    f16x8 p1 = *(const f16x8*)&P[wave][l16][32 + quad * 8];
    #pragma unroll
    for (int dt = 0; dt < 4; ++dt) {
      f16x8 v0 = *(const f16x8*)&vb[(size_t)(dt * 16 + l16) * 2048 + kv0 + quad * 8];
      f16x8 v1 = *(const f16x8*)&vb[(size_t)(dt * 16 + l16) * 2048 + kv0 + 32 + quad * 8];
      o[dt] = __builtin_amdgcn_mfma_f32_16x16x32_f16(p0, v0, o[dt], 0, 0, 0);
      o[dt] = __builtin_amdgcn_mfma_f32_16x16x32_f16(p1, v1, o[dt], 0, 0, 0);
    }
  }

  // publish per-wave partials
  #pragma unroll
  for (int dt = 0; dt < 4; ++dt)
    #pragma unroll
    for (int r = 0; r < 4; ++r)
      ob[wave][quad * 4 + r][dt * 16 + l16] = o[dt][r];
  if (l16 == 0) {
    #pragma unroll
    for (int r = 0; r < 4; ++r) {
      mlb[wave][0][quad * 4 + r] = mrow[r];
      mlb[wave][1][quad * 4 + r] = lrow[r];
    }
  }
  __syncthreads();

  // merge 4 splits; thread t -> row t>>4, cols (t&15)*4..+3
  {
    int row = tid >> 4;
    int c0  = (tid & 15) * 4;
    float m0 = mlb[0][0][row], m1 = mlb[1][0][row];
    float m2 = mlb[2][0][row], m3 = mlb[3][0][row];
    float M  = fmaxf(fmaxf(m0, m1), fmaxf(m2, m3));
    float w0 = exp2f((m0 - M) * L2E), w1 = exp2f((m1 - M) * L2E);
    float w2 = exp2f((m2 - M) * L2E), w3 = exp2f((m3 - M) * L2E);
    float L  = w0 * mlb[0][1][row] + w1 * mlb[1][1][row]
             + w2 * mlb[2][1][row] + w3 * mlb[3][1][row];
    float inv = 1.0f / (L * 32.0f);            // sqrt(H)=32 applied AFTER softmax
    f32x4 res;
    #pragma unroll
    for (int j = 0; j < 4; ++j)
      res[j] = (w0 * ob[0][row][c0 + j] + w1 * ob[1][row][c0 + j]
              + w2 * ob[2][row][c0 + j] + w3 * ob[3][row][c0 + j]) * inv;
    *(f32x4*)&out[((size_t)b * 2048 + q0 + row) * 64 + c0] = res;
  }
}

// ---------------------------------------------------------------------------
extern "C" void kernel_launch(void* const* d_in, const int* in_sizes, int n_in,
                              void* d_out, int out_size, void* d_ws, size_t ws_size,
                              hipStream_t stream) {
  const float* x  = (const float*)d_in[0];
  const float* Wq = (const float*)d_in[1];
  const float* bq = (const float*)d_in[2];
  const float* Wk = (const float*)d_in[3];
  const float* bk = (const float*)d_in[4];
  const float* Wv = (const float*)d_in[5];
  const float* bv = (const float*)d_in[6];
  float* out = (float*)d_out;

  // ws layout (f16): WtF 192*1024 | q 16384*64 | k 16384*64 | vt 8*64*2048 (~6.7MB)
  _Float16* WtF = (_Float16*)d_ws;
  _Float16* qo  = WtF + 192 * 1024;
  _Float16* ko  = qo + 16384 * 64;
  _Float16* vt  = ko + 16384 * 64;

  hipLaunchKernelGGL(wt_prep,  dim3(48),   dim3(256), 0, stream, Wq, Wk, Wv, WtF);
  hipLaunchKernelGGL(qkv_gemm, dim3(512),  dim3(512), 0, stream, x, WtF, bq, bk, bv, qo, ko, vt);
  hipLaunchKernelGGL(attn,     dim3(1024), dim3(256), 0, stream, qo, ko, vt, out);
}